// Round 3
// baseline (344.245 us; speedup 1.0000x reference)
//
#include <hip/hip_runtime.h>

// Gather + ragged segment XOR reduction.
// R1: 5 scalar gathers/token, 146 us. R2: padded 32B rows, 2 gathers/token,
// 142 us -> transaction count is NOT the bound. Cold (HBM) and steady (L3)
// dispatches both ~142 us -> bound is the L2-miss path (every random gather
// misses the 4 MB per-XCD L2 on a 32 MB table).
// R3: region-phased gather. Wave holds its <=127 idx in registers (2/lane),
// sweeps 16 regions x 65536 rows (2 MB padded, L2-resident on every XCD);
// pass r gathers only idx>>16==r. Each token gathered exactly once; XOR accum
// across passes in registers; no atomics. __syncthreads per pass keeps a
// block's 4 hint-waves phase-aligned; blocks launch roughly in order.

#define REG_SHIFT 16   // 65536 rows/region = 2 MB padded

__global__ __launch_bounds__(256) void pad_entries(
    const int* __restrict__ e, int* __restrict__ p, long n8)
{
    long i = (long)blockIdx.x * blockDim.x + threadIdx.x;
    if (i >= n8) return;
    long r = i >> 3;
    int  c = (int)(i & 7);
    p[i] = (c < 5) ? e[r * 5 + c] : 0;
}

__global__ __launch_bounds__(256) void hint_xor_phased(
    const int* __restrict__ padded,   // [N,8] int32, 32B rows
    const int* __restrict__ blocks,
    const int* __restrict__ offsets,
    const int* __restrict__ starts,
    const int* __restrict__ sizes,
    const int* __restrict__ bs_ptr,
    int* __restrict__ out,
    int H, int N, int nReg)
{
    const int gtid = blockIdx.x * blockDim.x + threadIdx.x;
    const int hint = gtid >> 6;
    const int lane = gtid & 63;
    const bool valid = hint < H;

    const int start = valid ? starts[hint] : 0;
    const int size  = valid ? sizes[hint] : 0;
    const int bs    = bs_ptr[0];

    // Preload this wave's token indices into registers (sizes < 128 -> 2 slots).
    const int j0 = lane;
    const int j1 = lane + 64;
    int idx0 = -1, idx1 = -1;
    if (j0 < size) {
        int v = blocks[start + j0] * bs + offsets[start + j0];
        idx0 = min(max(v, 0), N - 1);
    }
    if (j1 < size) {
        int v = blocks[start + j1] * bs + offsets[start + j1];
        idx1 = min(max(v, 0), N - 1);
    }

    int a0 = 0, a1 = 0, a2 = 0, a3 = 0, a4 = 0;

    for (int r = 0; r < nReg; ++r) {
        if ((idx0 >> REG_SHIFT) == r) {          // -1 >> 16 == -1, never matches
            const int* row = padded + ((size_t)idx0 << 3);
            int4 v = *(const int4*)row;
            int  f = row[4];
            a0 ^= v.x; a1 ^= v.y; a2 ^= v.z; a3 ^= v.w; a4 ^= f;
        }
        if ((idx1 >> REG_SHIFT) == r) {
            const int* row = padded + ((size_t)idx1 << 3);
            int4 v = *(const int4*)row;
            int  f = row[4];
            a0 ^= v.x; a1 ^= v.y; a2 ^= v.z; a3 ^= v.w; a4 ^= f;
        }
        __syncthreads();   // uniform: all waves run all nReg passes
    }

    #pragma unroll
    for (int m = 1; m < 64; m <<= 1) {
        a0 ^= __shfl_xor(a0, m);
        a1 ^= __shfl_xor(a1, m);
        a2 ^= __shfl_xor(a2, m);
        a3 ^= __shfl_xor(a3, m);
        a4 ^= __shfl_xor(a4, m);
    }

    if (valid && lane < 5) {
        int v = (lane == 0) ? a0 : (lane == 1) ? a1 : (lane == 2) ? a2
              : (lane == 3) ? a3 : a4;
        out[(size_t)hint * 5 + lane] = v;
    }
}

// Fallback (R1-style) if ws can't hold the padded table.
__global__ __launch_bounds__(256) void hint_xor_wave(
    const int* __restrict__ entries,
    const int* __restrict__ blocks,
    const int* __restrict__ offsets,
    const int* __restrict__ starts,
    const int* __restrict__ sizes,
    const int* __restrict__ bs_ptr,
    int* __restrict__ out,
    int H, int N)
{
    const int gtid = blockIdx.x * blockDim.x + threadIdx.x;
    const int hint = gtid >> 6;
    const int lane = gtid & 63;
    if (hint >= H) return;

    const int start = starts[hint];
    const int size  = sizes[hint];
    const int bs    = bs_ptr[0];

    int a0 = 0, a1 = 0, a2 = 0, a3 = 0, a4 = 0;
    for (int j = lane; j < size; j += 64) {
        int idx = blocks[start + j] * bs + offsets[start + j];
        idx = min(max(idx, 0), N - 1);
        const int* row = entries + (size_t)idx * 5;
        a0 ^= row[0]; a1 ^= row[1]; a2 ^= row[2]; a3 ^= row[3]; a4 ^= row[4];
    }
    #pragma unroll
    for (int m = 1; m < 64; m <<= 1) {
        a0 ^= __shfl_xor(a0, m);
        a1 ^= __shfl_xor(a1, m);
        a2 ^= __shfl_xor(a2, m);
        a3 ^= __shfl_xor(a3, m);
        a4 ^= __shfl_xor(a4, m);
    }
    if (lane == 0) {
        int* o = out + (size_t)hint * 5;
        o[0] = a0; o[1] = a1; o[2] = a2; o[3] = a3; o[4] = a4;
    }
}

extern "C" void kernel_launch(void* const* d_in, const int* in_sizes, int n_in,
                              void* d_out, int out_size, void* d_ws, size_t ws_size,
                              hipStream_t stream) {
    const int* entries = (const int*)d_in[0];
    const int* blocks  = (const int*)d_in[1];
    const int* offsets = (const int*)d_in[2];
    const int* starts  = (const int*)d_in[3];
    const int* sizes   = (const int*)d_in[4];
    const int* bs      = (const int*)d_in[5];
    int* out = (int*)d_out;

    const int H = in_sizes[3];
    const int N = in_sizes[0] / 5;

    const long total_threads = (long)H * 64;
    const int block = 256;
    const int grid = (int)((total_threads + block - 1) / block);

    const size_t pad_bytes = (size_t)N * 8 * sizeof(int);
    if (ws_size >= pad_bytes) {
        int* padded = (int*)d_ws;
        const long n8 = (long)N * 8;
        const int pgrid = (int)((n8 + block - 1) / block);
        hipLaunchKernelGGL(pad_entries, dim3(pgrid), dim3(block), 0, stream,
                           entries, padded, n8);
        const int nReg = (N + (1 << REG_SHIFT) - 1) >> REG_SHIFT;
        hipLaunchKernelGGL(hint_xor_phased, dim3(grid), dim3(block), 0, stream,
                           padded, blocks, offsets, starts, sizes, bs, out,
                           H, N, nReg);
    } else {
        hipLaunchKernelGGL(hint_xor_wave, dim3(grid), dim3(block), 0, stream,
                           entries, blocks, offsets, starts, sizes, bs, out, H, N);
    }
}

// Round 4
// 220.806 us; speedup vs baseline: 1.5590x; 1.5590x over previous
//
#include <hip/hip_runtime.h>

// Gather + ragged segment XOR reduction.
// R1/R2: every gather misses L2 (20-32 MB table vs 4 MB/XCD) -> flat 3.7 TB/s
// line-fill bound, 142 us, independent of request count. R3: loose phasing
// failed (non-persistent blocks drift; FETCH unchanged).
// R4: address-partitioned slices pinned to XCDs. Kernel A buckets tokens by
// slice (idx>>16, 16 slices x 1.31 MB packed). Kernel B launches exactly the
// resident capacity (2048 blocks); block (x,g) with x=blockIdx&7 processes
// slices {x, x+8} only -> each XCD's L2 holds a fixed 2.62 MB slice pair.
// Partial parities accumulate in LDS, then global atomicXor into zeroed out.

#define HPG     256     // hints per group
#define NSL     16      // slices (idx>>16), N <= 2^20
#define LDS_CAP 19456   // staged tokens per group (mean 16384, +5.3 sigma)

__device__ __forceinline__ int clip_idx(int v, int N) {
    return min(max(v, 0), N - 1);
}

// ---------------- Kernel A: bucket tokens by slice ----------------
__global__ __launch_bounds__(256) void bucket_kernel(
    const int* __restrict__ blocks,
    const int* __restrict__ offsets,
    const int* __restrict__ starts,
    const int* __restrict__ bs_ptr,
    const int* __restrict__ entries,   // only for rare overflow path
    int* __restrict__ out,             // only for rare overflow path
    unsigned short* __restrict__ bIdxLo,
    unsigned char*  __restrict__ bHint,
    unsigned int*   __restrict__ chunkTab,  // [NG*NSL*2] {base,count}
    unsigned int*   __restrict__ cursor,
    int H, int N, int T)
{
    __shared__ unsigned int w[LDS_CAP];
    __shared__ int lstart[HPG + 1];
    __shared__ unsigned int cnt[NSL], lbase[NSL], lcur[NSL];

    const int g  = blockIdx.x;
    const int t  = threadIdx.x;
    const int h0 = g * HPG;
    const int h1 = min(H, h0 + HPG);
    const int nh = h1 - h0;
    const int bs = bs_ptr[0];

    for (int i = t; i < nh; i += 256) lstart[i] = starts[h0 + i];
    if (t == 0) lstart[nh] = (h1 < H) ? starts[h1] : T;
    if (t < NSL) { cnt[t] = 0; lcur[t] = 0; }
    __syncthreads();

    const int tokBase = lstart[0];
    const int count   = lstart[nh] - tokBase;
    const int staged  = min(count, LDS_CAP);

    // pass 1: compute idx+slice, stage, histogram
    for (int i = t; i < staged; i += 256) {
        int b = blocks[tokBase + i];
        int o = offsets[tokBase + i];
        int idx = clip_idx(b * bs + o, N);
        unsigned int s = (unsigned int)idx >> 16;
        w[i] = (unsigned int)(idx & 0xFFFF) | (s << 24);
        atomicAdd(&cnt[s], 1u);
    }
    __syncthreads();

    // pass 2: fill local-hint byte (thread t owns local hint t)
    if (t < nh) {
        int lo = lstart[t] - tokBase;
        int hi = min(lstart[t + 1] - tokBase, staged);
        for (int i = lo; i < hi; ++i) w[i] |= ((unsigned int)t << 16);
    }
    __syncthreads();

    // claim global chunk space
    if (t < NSL) {
        unsigned int base = atomicAdd(cursor, cnt[t]);
        lbase[t] = base;
        chunkTab[(g * NSL + t) * 2 + 0] = base;
        chunkTab[(g * NSL + t) * 2 + 1] = cnt[t];
    }
    __syncthreads();

    // scatter (unstable but clustered: same-instruction ranks are adjacent)
    for (int i = t; i < staged; i += 256) {
        unsigned int wd = w[i];
        unsigned int s  = wd >> 24;
        unsigned int r  = atomicAdd(&lcur[s], 1u);
        unsigned int p  = lbase[s] + r;
        bIdxLo[p] = (unsigned short)(wd & 0xFFFF);
        bHint[p]  = (unsigned char)((wd >> 16) & 0xFF);
    }

    // overflow path (count > LDS_CAP): direct gather + global atomicXor.
    // Statistically never runs at these sizes; kept for correctness.
    for (int i = staged + t; i < count; i += 256) {
        int b = blocks[tokBase + i];
        int o = offsets[tokBase + i];
        int idx = clip_idx(b * bs + o, N);
        int gpos = tokBase + i;
        int lo = 0, hi = nh - 1;
        while (lo < hi) {              // largest h with lstart[h] <= gpos
            int m = (lo + hi + 1) >> 1;
            if (lstart[m] <= gpos) lo = m; else hi = m - 1;
        }
        const int* row = entries + (long)idx * 5;
        int* o5 = out + (long)(h0 + lo) * 5;
        atomicXor(&o5[0], row[0]); atomicXor(&o5[1], row[1]);
        atomicXor(&o5[2], row[2]); atomicXor(&o5[3], row[3]);
        atomicXor(&o5[4], row[4]);
    }
}

// ---------------- Kernel B: XCD-pinned gather + LDS accumulate ----------------
__global__ __launch_bounds__(256) void gather_kernel(
    const unsigned short* __restrict__ bIdxLo,
    const unsigned char*  __restrict__ bHint,
    const unsigned int*   __restrict__ chunkTab,
    const int* __restrict__ entries,
    int* __restrict__ out,
    int H, int NG, int nSl, int groupsPerBlock)
{
    __shared__ int acc[HPG * 5];
    const int B = blockIdx.x;
    const int x = B & 7;            // intended XCD (round-robin dispatch)
    const int g0 = B >> 3;
    const int t = threadIdx.x;
    const int gStride = gridDim.x >> 3;

    for (int k = 0; k < groupsPerBlock; ++k) {
        const int g = g0 + k * gStride;
        if (g >= NG) break;

        for (int i = t; i < HPG * 5; i += 256) acc[i] = 0;
        __syncthreads();

        for (int s = x; s < nSl; s += 8) {
            const unsigned int base = chunkTab[(g * NSL + s) * 2 + 0];
            const unsigned int cn   = chunkTab[(g * NSL + s) * 2 + 1];
            const int hiBits = s << 16;
            for (unsigned int i = t; i < cn; i += 256) {
                int idx = hiBits | (int)bIdxLo[base + i];
                int h   = (int)bHint[base + i];
                const int* row = entries + (long)idx * 5;
                atomicXor(&acc[h * 5 + 0], row[0]);
                atomicXor(&acc[h * 5 + 1], row[1]);
                atomicXor(&acc[h * 5 + 2], row[2]);
                atomicXor(&acc[h * 5 + 3], row[3]);
                atomicXor(&acc[h * 5 + 4], row[4]);
            }
        }
        __syncthreads();

        const long obase = (long)g * HPG * 5;
        const long omax  = (long)H * 5;
        for (int i = t; i < HPG * 5; i += 256) {
            if (obase + i < omax && acc[i] != 0)
                atomicXor(&out[obase + i], acc[i]);
        }
        __syncthreads();
    }
}

// ---------------- Fallback (R1): direct gather, wave per hint ----------------
__global__ __launch_bounds__(256) void hint_xor_wave(
    const int* __restrict__ entries,
    const int* __restrict__ blocks,
    const int* __restrict__ offsets,
    const int* __restrict__ starts,
    const int* __restrict__ sizes,
    const int* __restrict__ bs_ptr,
    int* __restrict__ out,
    int H, int N)
{
    const int gtid = blockIdx.x * blockDim.x + threadIdx.x;
    const int hint = gtid >> 6;
    const int lane = gtid & 63;
    if (hint >= H) return;

    const int start = starts[hint];
    const int size  = sizes[hint];
    const int bs    = bs_ptr[0];

    int a0 = 0, a1 = 0, a2 = 0, a3 = 0, a4 = 0;
    for (int j = lane; j < size; j += 64) {
        int idx = clip_idx(blocks[start + j] * bs + offsets[start + j], N);
        const int* row = entries + (size_t)idx * 5;
        a0 ^= row[0]; a1 ^= row[1]; a2 ^= row[2]; a3 ^= row[3]; a4 ^= row[4];
    }
    #pragma unroll
    for (int m = 1; m < 64; m <<= 1) {
        a0 ^= __shfl_xor(a0, m);
        a1 ^= __shfl_xor(a1, m);
        a2 ^= __shfl_xor(a2, m);
        a3 ^= __shfl_xor(a3, m);
        a4 ^= __shfl_xor(a4, m);
    }
    if (lane == 0) {
        int* o = out + (size_t)hint * 5;
        o[0] = a0; o[1] = a1; o[2] = a2; o[3] = a3; o[4] = a4;
    }
}

extern "C" void kernel_launch(void* const* d_in, const int* in_sizes, int n_in,
                              void* d_out, int out_size, void* d_ws, size_t ws_size,
                              hipStream_t stream) {
    const int* entries = (const int*)d_in[0];
    const int* blocks  = (const int*)d_in[1];
    const int* offsets = (const int*)d_in[2];
    const int* starts  = (const int*)d_in[3];
    const int* sizes   = (const int*)d_in[4];
    const int* bs      = (const int*)d_in[5];
    int* out = (int*)d_out;

    const int H = in_sizes[3];
    const int T = in_sizes[1];
    const int N = in_sizes[0] / 5;

    const int NG  = (H + HPG - 1) / HPG;
    const int nSl = (N + 65535) >> 16;

    // ws layout
    const size_t cursorOff = 0;                           // 4 B
    const size_t tabOff    = 64;                          // NG*NSL*2 u32
    const size_t loOff     = tabOff + (size_t)NG * NSL * 2 * 4;
    const size_t hOff      = loOff + (size_t)T * 2;
    const size_t need      = hOff + (size_t)T + 64;

    const bool ok = (N <= (1 << 20)) && (nSl <= NSL) && (ws_size >= need) &&
                    (NG >= 8);

    if (ok) {
        unsigned int*   cursor   = (unsigned int*)((char*)d_ws + cursorOff);
        unsigned int*   chunkTab = (unsigned int*)((char*)d_ws + tabOff);
        unsigned short* bIdxLo   = (unsigned short*)((char*)d_ws + loOff);
        unsigned char*  bHint    = (unsigned char*)((char*)d_ws + hOff);

        hipMemsetAsync(d_out, 0, (size_t)out_size * sizeof(int), stream);
        hipMemsetAsync(cursor, 0, sizeof(unsigned int), stream);

        hipLaunchKernelGGL(bucket_kernel, dim3(NG), dim3(256), 0, stream,
                           blocks, offsets, starts, bs, entries, out,
                           bIdxLo, bHint, chunkTab, cursor, H, N, T);

        // grid B = 2048 (resident capacity: 8 blocks/CU x 256 CU) so that
        // blockIdx&7 -> XCD round-robin holds for the whole kernel.
        int gridB = 2048;
        if (gridB > NG * 8) gridB = NG * 8;   // small-H safety
        const int gStride = gridB >> 3;
        const int gpb = (NG + gStride - 1) / gStride;

        hipLaunchKernelGGL(gather_kernel, dim3(gridB), dim3(256), 0, stream,
                           bIdxLo, bHint, chunkTab, entries, out,
                           H, NG, nSl, gpb);
    } else {
        const long total_threads = (long)H * 64;
        const int block = 256;
        const int grid = (int)((total_threads + block - 1) / block);
        hipLaunchKernelGGL(hint_xor_wave, dim3(grid), dim3(block), 0, stream,
                           entries, blocks, offsets, starts, sizes, bs, out, H, N);
    }
}